// Round 3
// baseline (1255.454 us; speedup 1.0000x reference)
//
#include <hip/hip_runtime.h>

typedef __bf16 bf16;
typedef __bf16 bf16x8 __attribute__((ext_vector_type(8)));
typedef float f32x4 __attribute__((ext_vector_type(4)));

#define S_LEN 2048
#define HID 4096
#define NH 32
#define NKV 8
#define HD 128

// load 8 contiguous elements as bf16x8, from either bf16 or fp32 global memory
__device__ inline bf16x8 load8(const bf16* p) { return *(const bf16x8*)p; }
__device__ inline bf16x8 load8(const float* p) {
    float4 a = *(const float4*)p;
    float4 b = *(const float4*)(p + 4);
    bf16x8 r;
    r[0] = (bf16)a.x; r[1] = (bf16)a.y; r[2] = (bf16)a.z; r[3] = (bf16)a.w;
    r[4] = (bf16)b.x; r[5] = (bf16)b.y; r[6] = (bf16)b.z; r[7] = (bf16)b.w;
    return r;
}

// ---------------------------------------------------------------------------
// GEMM: out[M,N] = A[M,K] @ W[N,K]^T + bias[N]   (bf16 MFMA, fp32 accum)
// 128x128 tile, BK=64, 256 threads = 4 waves in 2x2, each wave 64x64.
// A is fp32 or bf16; W is fp32; out is bf16 or fp32 (TO).
// ---------------------------------------------------------------------------
template <typename TA, typename TO>
__global__ __launch_bounds__(256) void gemm_bt(const TA* __restrict__ A,
                                               const float* __restrict__ W,
                                               const float* __restrict__ bias,
                                               TO* __restrict__ out,
                                               int N, int K) {
    __shared__ __align__(16) bf16 As[128 * 64];
    __shared__ __align__(16) bf16 Bs[128 * 64];

    const int tid  = threadIdx.x;
    const int wave = tid >> 6;
    const int lane = tid & 63;
    const int quad = lane >> 4;
    const int l16  = lane & 15;
    const int wm   = wave >> 1;   // 0..1
    const int wn   = wave & 1;    // 0..1
    const int row0 = blockIdx.y * 128;
    const int col0 = blockIdx.x * 128;

    f32x4 acc[4][4];
#pragma unroll
    for (int mi = 0; mi < 4; ++mi)
#pragma unroll
        for (int ni = 0; ni < 4; ++ni) {
            f32x4 z = {0.f, 0.f, 0.f, 0.f};
            acc[mi][ni] = z;
        }

    for (int k0 = 0; k0 < K; k0 += 64) {
        // stage A-tile [128][64] and W-tile [128][64], converting to bf16
#pragma unroll
        for (int i = 0; i < 4; ++i) {
            int c    = i * 256 + tid;    // 0..1023
            int r    = c >> 3;           // 0..127
            int col8 = (c & 7) << 3;     // 0..56
            *(bf16x8*)&As[r * 64 + col8] = load8(&A[(size_t)(row0 + r) * K + k0 + col8]);
            *(bf16x8*)&Bs[r * 64 + col8] = load8(&W[(size_t)(col0 + r) * K + k0 + col8]);
        }
        __syncthreads();

#pragma unroll
        for (int ks = 0; ks < 2; ++ks) {
            bf16x8 af[4], bfr[4];
#pragma unroll
            for (int mi = 0; mi < 4; ++mi)
                af[mi] = *(const bf16x8*)&As[(wm * 64 + mi * 16 + l16) * 64 + ks * 32 + quad * 8];
#pragma unroll
            for (int ni = 0; ni < 4; ++ni)
                bfr[ni] = *(const bf16x8*)&Bs[(wn * 64 + ni * 16 + l16) * 64 + ks * 32 + quad * 8];
#pragma unroll
            for (int mi = 0; mi < 4; ++mi)
#pragma unroll
                for (int ni = 0; ni < 4; ++ni)
                    acc[mi][ni] = __builtin_amdgcn_mfma_f32_16x16x32_bf16(
                        af[mi], bfr[ni], acc[mi][ni], 0, 0, 0);
        }
        __syncthreads();
    }

    // epilogue: D col = lane&15, row = quad*4 + reg
#pragma unroll
    for (int ni = 0; ni < 4; ++ni) {
        int n    = col0 + wn * 64 + ni * 16 + l16;
        float bv = bias[n];
#pragma unroll
        for (int mi = 0; mi < 4; ++mi) {
            int m = row0 + wm * 64 + mi * 16 + quad * 4;
#pragma unroll
            for (int reg = 0; reg < 4; ++reg)
                out[(size_t)(m + reg) * N + n] = (TO)(acc[mi][ni][reg] + bv);
        }
    }
}

// ---------------------------------------------------------------------------
// Per-(s,head) LayerNorm over HD=128 + RoPE, in place on bf16 workspace.
// One wave per row. Lane l owns elements (l, l+64) — the rotate_half pairing.
// ---------------------------------------------------------------------------
__global__ __launch_bounds__(256) void ln_rope(bf16* __restrict__ qb, bf16* __restrict__ kb,
                                               const float* __restrict__ qg, const float* __restrict__ qbt,
                                               const float* __restrict__ kg, const float* __restrict__ kbt) {
    int row  = blockIdx.x * 4 + (threadIdx.x >> 6);
    int lane = threadIdx.x & 63;

    bf16* ptr;
    const float *g, *bb;
    int s;
    if (row < S_LEN * NH) {
        s   = row >> 5;
        ptr = qb + (size_t)s * (NH * HD) + (row & 31) * HD;
        g   = qg; bb = qbt;
    } else {
        int r2 = row - S_LEN * NH;
        s   = r2 >> 3;
        ptr = kb + (size_t)s * (NKV * HD) + (r2 & 7) * HD;
        g   = kg; bb = kbt;
    }

    float x1 = (float)ptr[lane];
    float x2 = (float)ptr[lane + 64];
    float sum = x1 + x2;
    float sq  = x1 * x1 + x2 * x2;
#pragma unroll
    for (int m = 1; m < 64; m <<= 1) {
        sum += __shfl_xor(sum, m);
        sq  += __shfl_xor(sq, m);
    }
    float mu  = sum * (1.f / 128.f);
    float var = sq * (1.f / 128.f) - mu * mu;
    float rs  = rsqrtf(var + 1e-5f);
    float n1  = (x1 - mu) * rs * g[lane] + bb[lane];
    float n2  = (x2 - mu) * rs * g[lane + 64] + bb[lane + 64];

    float inv = powf(500000.f, -(float)lane * (1.f / 64.f));
    float ang = (float)s * inv;
    float sn, cs;
    sincosf(ang, &sn, &cs);

    ptr[lane]      = (bf16)(n1 * cs - n2 * sn);
    ptr[lane + 64] = (bf16)(n2 * cs + n1 * sn);
}

// ---------------------------------------------------------------------------
// Flash attention, causal, GQA 4:1. One block = (head h, 64-row Q tile qi).
// 4 waves; each wave owns a 16-row strip. Softmax via LDS round-trip.
// ---------------------------------------------------------------------------
__global__ __launch_bounds__(256) void attn(const bf16* __restrict__ qbuf,
                                            const bf16* __restrict__ kbuf,
                                            const bf16* __restrict__ vbuf,
                                            bf16* __restrict__ obuf) {
    const int qi  = blockIdx.x;   // 0..31
    const int h   = blockIdx.y;   // 0..31
    const int kvh = h >> 2;

    __shared__ __align__(16) bf16 Qs[64 * 128];
    __shared__ __align__(16) bf16 Ks[64 * 128];
    __shared__ __align__(16) bf16 Vt[128 * 80];   // transposed V: [d][key], pad to 80
    __shared__ __align__(16) float Ss[64 * 64];
    __shared__ __align__(16) bf16 Ps[64 * 64];
    __shared__ float mS[64], lS[64], aS[64];

    const int tid  = threadIdx.x;
    const int wave = tid >> 6;
    const int lane = tid & 63;
    const int quad = lane >> 4;
    const int l16  = lane & 15;

    // stage Q tile [64][128]
#pragma unroll
    for (int i = 0; i < 4; ++i) {
        int c    = i * 256 + tid;          // 1024 chunks
        int r    = c >> 4;
        int col8 = (c & 15) << 3;
        *(int4*)&Qs[r * 128 + col8] =
            *(const int4*)&qbuf[(size_t)(qi * 64 + r) * HID + h * HD + col8];
    }
    if (tid < 64) { mS[tid] = -1e30f; lS[tid] = 0.f; }

    f32x4 o_acc[8];
#pragma unroll
    for (int i = 0; i < 8; ++i) {
        f32x4 z = {0.f, 0.f, 0.f, 0.f};
        o_acc[i] = z;
    }
    __syncthreads();

    const float scale = 0.08838834764831845f;  // 1/sqrt(128)

    for (int kt = 0; kt <= qi; ++kt) {
        // stage K tile [64][128] and V^T tile [128][64]
#pragma unroll
        for (int i = 0; i < 4; ++i) {
            int c    = i * 256 + tid;
            int r    = c >> 4;
            int col8 = (c & 15) << 3;
            const size_t gofs = (size_t)(kt * 64 + r) * (NKV * HD) + kvh * HD + col8;
            *(int4*)&Ks[r * 128 + col8] = *(const int4*)&kbuf[gofs];
            bf16x8 vv = *(const bf16x8*)&vbuf[gofs];
#pragma unroll
            for (int e = 0; e < 8; ++e) Vt[(col8 + e) * 80 + r] = vv[e];
        }
        __syncthreads();

        // S strip: 16 rows x 64 cols per wave
        f32x4 sacc[4];
#pragma unroll
        for (int ni = 0; ni < 4; ++ni) {
            f32x4 z = {0.f, 0.f, 0.f, 0.f};
            sacc[ni] = z;
        }
#pragma unroll
        for (int ks = 0; ks < 4; ++ks) {
            bf16x8 a = *(const bf16x8*)&Qs[(wave * 16 + l16) * 128 + ks * 32 + quad * 8];
#pragma unroll
            for (int ni = 0; ni < 4; ++ni) {
                bf16x8 b = *(const bf16x8*)&Ks[(ni * 16 + l16) * 128 + ks * 32 + quad * 8];
                sacc[ni] = __builtin_amdgcn_mfma_f32_16x16x32_bf16(a, b, sacc[ni], 0, 0, 0);
            }
        }
        // write scaled+masked scores
#pragma unroll
        for (int ni = 0; ni < 4; ++ni) {
#pragma unroll
            for (int reg = 0; reg < 4; ++reg) {
                int r    = wave * 16 + quad * 4 + reg;
                int cc   = ni * 16 + l16;
                int rowg = qi * 64 + r;
                int colg = kt * 64 + cc;
                float sv = sacc[ni][reg] * scale;
                if (colg > rowg) sv = -1e30f;
                Ss[r * 64 + cc] = sv;
            }
        }
        __syncthreads();

        // online softmax: 4 threads per row, 16 cols each
        {
            int r = tid >> 2, j = tid & 3;
            float vals[16];
            float mloc = -1e30f;
#pragma unroll
            for (int c = 0; c < 16; ++c) {
                vals[c] = Ss[r * 64 + j * 16 + c];
                mloc = fmaxf(mloc, vals[c]);
            }
            mloc = fmaxf(mloc, __shfl_xor(mloc, 1));
            mloc = fmaxf(mloc, __shfl_xor(mloc, 2));
            float mold = mS[r];
            float mnew = fmaxf(mold, mloc);
            float ssum = 0.f;
#pragma unroll
            for (int c = 0; c < 16; ++c) {
                float p = __expf(vals[c] - mnew);
                ssum += p;
                Ps[r * 64 + j * 16 + c] = (bf16)p;
            }
            ssum += __shfl_xor(ssum, 1);
            ssum += __shfl_xor(ssum, 2);
            if (j == 0) {
                float alpha = __expf(mold - mnew);
                mS[r] = mnew;
                lS[r] = lS[r] * alpha + ssum;
                aS[r] = alpha;
            }
        }
        __syncthreads();

        // rescale O by alpha, accumulate P @ V
        {
            float al[4];
#pragma unroll
            for (int reg = 0; reg < 4; ++reg) al[reg] = aS[wave * 16 + quad * 4 + reg];
#pragma unroll
            for (int ni = 0; ni < 8; ++ni)
#pragma unroll
                for (int reg = 0; reg < 4; ++reg) o_acc[ni][reg] *= al[reg];
#pragma unroll
            for (int ks = 0; ks < 2; ++ks) {
                bf16x8 a = *(const bf16x8*)&Ps[(wave * 16 + l16) * 64 + ks * 32 + quad * 8];
#pragma unroll
                for (int ni = 0; ni < 8; ++ni) {
                    bf16x8 b = *(const bf16x8*)&Vt[(ni * 16 + l16) * 80 + ks * 32 + quad * 8];
                    o_acc[ni] = __builtin_amdgcn_mfma_f32_16x16x32_bf16(a, b, o_acc[ni], 0, 0, 0);
                }
            }
        }
        __syncthreads();
    }

    // epilogue: O /= l, write [s][h*128+d]
    {
        float linv[4];
#pragma unroll
        for (int reg = 0; reg < 4; ++reg)
            linv[reg] = 1.f / fmaxf(lS[wave * 16 + quad * 4 + reg], 1e-20f);
#pragma unroll
        for (int ni = 0; ni < 8; ++ni) {
#pragma unroll
            for (int reg = 0; reg < 4; ++reg) {
                int r = wave * 16 + quad * 4 + reg;
                int s = qi * 64 + r;
                int d = ni * 16 + l16;
                obuf[(size_t)s * HID + h * HD + d] = (bf16)(o_acc[ni][reg] * linv[reg]);
            }
        }
    }
}

// ---------------------------------------------------------------------------
extern "C" void kernel_launch(void* const* d_in, const int* in_sizes, int n_in,
                              void* d_out, int out_size, void* d_ws, size_t ws_size,
                              hipStream_t stream) {
    const float* x   = (const float*)d_in[0];
    const float* Wq  = (const float*)d_in[1];
    const float* bq  = (const float*)d_in[2];
    const float* Wk  = (const float*)d_in[3];
    const float* bk  = (const float*)d_in[4];
    const float* Wv  = (const float*)d_in[5];
    const float* bv  = (const float*)d_in[6];
    const float* Wo  = (const float*)d_in[7];
    const float* bo  = (const float*)d_in[8];
    const float* qg  = (const float*)d_in[9];
    const float* qbt = (const float*)d_in[10];
    const float* kg  = (const float*)d_in[11];
    const float* kbt = (const float*)d_in[12];
    float* out = (float*)d_out;   // reference output dtype is float32

    char* ws   = (char*)d_ws;
    bf16* qbuf = (bf16*)(ws);                    // 2048*4096*2 = 16 MB
    bf16* kbuf = (bf16*)(ws + (16u << 20));      // 2048*1024*2 =  4 MB
    bf16* vbuf = (bf16*)(ws + (20u << 20));      //               4 MB
    bf16* abuf = (bf16*)(ws + (24u << 20));      // 16 MB

    // QKV projections (fp32 in, bf16 out)
    gemm_bt<float, bf16><<<dim3(4096 / 128, 2048 / 128), 256, 0, stream>>>(x, Wq, bq, qbuf, 4096, 4096);
    gemm_bt<float, bf16><<<dim3(1024 / 128, 2048 / 128), 256, 0, stream>>>(x, Wk, bk, kbuf, 1024, 4096);
    gemm_bt<float, bf16><<<dim3(1024 / 128, 2048 / 128), 256, 0, stream>>>(x, Wv, bv, vbuf, 1024, 4096);

    // LayerNorm + RoPE on q and k (in place)
    ln_rope<<<dim3((S_LEN * (NH + NKV)) / 4), 256, 0, stream>>>(qbuf, kbuf, qg, qbt, kg, kbt);

    // causal GQA flash attention
    attn<<<dim3(S_LEN / 64, NH), 256, 0, stream>>>(qbuf, kbuf, vbuf, abuf);

    // output projection (bf16 A from workspace, fp32 W, fp32 out)
    gemm_bt<bf16, float><<<dim3(4096 / 128, 2048 / 128), 256, 0, stream>>>(abuf, Wo, bo, out, 4096, 4096);
}

// Round 4
// 814.410 us; speedup vs baseline: 1.5416x; 1.5416x over previous
//
#include <hip/hip_runtime.h>

typedef __bf16 bf16;
typedef __bf16 bf16x8 __attribute__((ext_vector_type(8)));
typedef float f32x4 __attribute__((ext_vector_type(4)));

#define S_LEN 2048
#define HID 4096
#define NH 32
#define NKV 8
#define HD 128
#define SCALE 0.08838834764831845f

// load 8 contiguous elements as bf16x8, from either bf16 or fp32 global memory
__device__ __forceinline__ bf16x8 load8(const bf16* p) { return *(const bf16x8*)p; }
__device__ __forceinline__ bf16x8 load8(const float* p) {
    float4 a = *(const float4*)p;
    float4 b = *(const float4*)(p + 4);
    bf16x8 r;
    r[0] = (bf16)a.x; r[1] = (bf16)a.y; r[2] = (bf16)a.z; r[3] = (bf16)a.w;
    r[4] = (bf16)b.x; r[5] = (bf16)b.y; r[6] = (bf16)b.z; r[7] = (bf16)b.w;
    return r;
}

// async global->LDS, 16 bytes per lane (dest must be wave-uniform base + lane*16)
__device__ __forceinline__ void load_lds16(const bf16* g, bf16* l) {
    __builtin_amdgcn_global_load_lds(
        (const __attribute__((address_space(1))) void*)g,
        (__attribute__((address_space(3))) void*)l, 16, 0, 0);
}

// ---------------------------------------------------------------------------
// fp32 -> bf16 bulk convert (8 elems/thread)
// ---------------------------------------------------------------------------
__global__ __launch_bounds__(256) void cvt(const float* __restrict__ in,
                                           bf16* __restrict__ out, int n8) {
    int i = blockIdx.x * 256 + threadIdx.x;
    if (i < n8) *(bf16x8*)&out[i * 8] = load8(&in[(size_t)i * 8]);
}

// ---------------------------------------------------------------------------
// m97-style GEMM: out[M,N] = A[M,K] @ B[N,K]^T + bias  (bf16 in, fp32 accum)
// 128x128 tile, BK=64, global_load_lds dwordx4 staging.
// BROW: bias indexed by output row (m) instead of column (n).
// ---------------------------------------------------------------------------
template <bool BROW, typename TO>
__global__ __launch_bounds__(256) void gemm_lds(const bf16* __restrict__ A,
                                                const bf16* __restrict__ Bw,
                                                const float* __restrict__ bias,
                                                TO* __restrict__ out,
                                                int N, int K) {
    __shared__ __align__(16) bf16 As[128 * 64];
    __shared__ __align__(16) bf16 Bs[128 * 64];

    const int tid  = threadIdx.x;
    const int wave = tid >> 6;
    const int lane = tid & 63;
    const int quad = lane >> 4;
    const int l16  = lane & 15;
    const int wm   = wave >> 1;
    const int wn   = wave & 1;
    const int row0 = blockIdx.y * 128;
    const int col0 = blockIdx.x * 128;

    f32x4 acc[4][4];
#pragma unroll
    for (int mi = 0; mi < 4; ++mi)
#pragma unroll
        for (int ni = 0; ni < 4; ++ni) {
            f32x4 z = {0.f, 0.f, 0.f, 0.f};
            acc[mi][ni] = z;
        }

    for (int k0 = 0; k0 < K; k0 += 64) {
#pragma unroll
        for (int i = 0; i < 4; ++i) {
            int c    = i * 256 + tid;     // 0..1023
            int r    = c >> 3;
            int col8 = (c & 7) << 3;
            load_lds16(&A[(size_t)(row0 + r) * K + k0 + col8], &As[c * 8]);
            load_lds16(&Bw[(size_t)(col0 + r) * K + k0 + col8], &Bs[c * 8]);
        }
        __syncthreads();

#pragma unroll
        for (int ks = 0; ks < 2; ++ks) {
            bf16x8 af[4], bfr[4];
#pragma unroll
            for (int mi = 0; mi < 4; ++mi)
                af[mi] = *(const bf16x8*)&As[(wm * 64 + mi * 16 + l16) * 64 + ks * 32 + quad * 8];
#pragma unroll
            for (int ni = 0; ni < 4; ++ni)
                bfr[ni] = *(const bf16x8*)&Bs[(wn * 64 + ni * 16 + l16) * 64 + ks * 32 + quad * 8];
#pragma unroll
            for (int mi = 0; mi < 4; ++mi)
#pragma unroll
                for (int ni = 0; ni < 4; ++ni)
                    acc[mi][ni] = __builtin_amdgcn_mfma_f32_16x16x32_bf16(
                        af[mi], bfr[ni], acc[mi][ni], 0, 0, 0);
        }
        __syncthreads();
    }

#pragma unroll
    for (int ni = 0; ni < 4; ++ni) {
        int n    = col0 + wn * 64 + ni * 16 + l16;
        float bn = BROW ? 0.f : bias[n];
#pragma unroll
        for (int mi = 0; mi < 4; ++mi) {
            int m = row0 + wm * 64 + mi * 16 + quad * 4;
#pragma unroll
            for (int reg = 0; reg < 4; ++reg) {
                float bv = BROW ? bias[m + reg] : bn;
                out[(size_t)(m + reg) * N + n] = (TO)(acc[mi][ni][reg] + bv);
            }
        }
    }
}

// ---------------------------------------------------------------------------
// Per-(s,head) LayerNorm over HD=128 + RoPE, in place on bf16 workspace.
// ---------------------------------------------------------------------------
__global__ __launch_bounds__(256) void ln_rope(bf16* __restrict__ qb, bf16* __restrict__ kb,
                                               const float* __restrict__ qg, const float* __restrict__ qbt,
                                               const float* __restrict__ kg, const float* __restrict__ kbt) {
    int row  = blockIdx.x * 4 + (threadIdx.x >> 6);
    int lane = threadIdx.x & 63;

    bf16* ptr;
    const float *g, *bb;
    int s;
    if (row < S_LEN * NH) {
        s   = row >> 5;
        ptr = qb + (size_t)s * (NH * HD) + (row & 31) * HD;
        g   = qg; bb = qbt;
    } else {
        int r2 = row - S_LEN * NH;
        s   = r2 >> 3;
        ptr = kb + (size_t)s * (NKV * HD) + (r2 & 7) * HD;
        g   = kg; bb = kbt;
    }

    float x1 = (float)ptr[lane];
    float x2 = (float)ptr[lane + 64];
    float sum = x1 + x2;
    float sq  = x1 * x1 + x2 * x2;
#pragma unroll
    for (int m = 1; m < 64; m <<= 1) {
        sum += __shfl_xor(sum, m);
        sq  += __shfl_xor(sq, m);
    }
    float mu  = sum * (1.f / 128.f);
    float var = sq * (1.f / 128.f) - mu * mu;
    float rs  = rsqrtf(var + 1e-5f);
    float n1  = (x1 - mu) * rs * g[lane] + bb[lane];
    float n2  = (x2 - mu) * rs * g[lane + 64] + bb[lane + 64];

    float inv = powf(500000.f, -(float)lane * (1.f / 64.f));
    float ang = (float)s * inv;
    float sn, cs;
    sincosf(ang, &sn, &cs);

    ptr[lane]      = (bf16)(n1 * cs - n2 * sn);
    ptr[lane + 64] = (bf16)(n2 * cs + n1 * sn);
}

// ---------------------------------------------------------------------------
// Flash attention v2: one block = 4 heads of one KV group, 32 Q-rows.
// Wave w owns head kvh*4+w. Q in registers, register online-softmax,
// P through per-wave swizzled LDS, K/V^T tiles XOR-8 swizzled.
// V comes in transposed: vbT[kv_col][s].
// ---------------------------------------------------------------------------
__global__ __launch_bounds__(256, 2) void attn2(const bf16* __restrict__ qbuf,
                                                const bf16* __restrict__ kbuf,
                                                const bf16* __restrict__ vbT,
                                                bf16* __restrict__ obuf) {
    const int qt   = (int)gridDim.x - 1 - (int)blockIdx.x;  // big tiles first
    const int kvh  = blockIdx.y;
    const int tid  = threadIdx.x;
    const int wave = tid >> 6;
    const int lane = tid & 63;
    const int quad = lane >> 4;
    const int l16  = lane & 15;
    const int h    = kvh * 4 + wave;
    const int r0   = qt * 32;

    __shared__ __align__(16) bf16 Ks[64 * 128];
    __shared__ __align__(16) bf16 Vt[128 * 64];
    __shared__ __align__(16) bf16 Ps[4][32 * 64];

    // Q fragments in registers: A[m=row][k=dim]
    bf16x8 qf[2][4];
#pragma unroll
    for (int mi = 0; mi < 2; ++mi)
#pragma unroll
        for (int ks = 0; ks < 4; ++ks)
            qf[mi][ks] = *(const bf16x8*)&qbuf[(size_t)(r0 + mi * 16 + l16) * HID +
                                               h * HD + ks * 32 + quad * 8];

    f32x4 o_acc[2][8];
#pragma unroll
    for (int mi = 0; mi < 2; ++mi)
#pragma unroll
        for (int ni = 0; ni < 8; ++ni) {
            f32x4 z = {0.f, 0.f, 0.f, 0.f};
            o_acc[mi][ni] = z;
        }
    float mrow[2][4], lrow[2][4];
#pragma unroll
    for (int mi = 0; mi < 2; ++mi)
#pragma unroll
        for (int reg = 0; reg < 4; ++reg) { mrow[mi][reg] = -1e30f; lrow[mi][reg] = 0.f; }

    const int nkt = qt / 2 + 1;
    for (int kt = 0; kt < nkt; ++kt) {
        // stage K [64 keys][128 d] and V^T [128 d][64 keys], XOR-8 swizzled
#pragma unroll
        for (int i = 0; i < 4; ++i) {
            int c   = i * 256 + tid;
            int key = c >> 4, d8 = c & 15;
            *(bf16x8*)&Ks[key * 128 + ((d8 ^ (key & 7)) << 3)] =
                *(const bf16x8*)&kbuf[(size_t)(kt * 64 + key) * (NKV * HD) + kvh * HD + (d8 << 3)];
            int d = c >> 3, k8 = c & 7;
            *(bf16x8*)&Vt[d * 64 + ((k8 ^ (d & 7)) << 3)] =
                *(const bf16x8*)&vbT[(size_t)(kvh * HD + d) * S_LEN + kt * 64 + (k8 << 3)];
        }
        __syncthreads();

        // S = Q K^T : 32 rows x 64 keys per wave
        f32x4 sacc[2][4];
#pragma unroll
        for (int mi = 0; mi < 2; ++mi)
#pragma unroll
            for (int ni = 0; ni < 4; ++ni) {
                f32x4 z = {0.f, 0.f, 0.f, 0.f};
                sacc[mi][ni] = z;
            }
#pragma unroll
        for (int ks = 0; ks < 4; ++ks)
#pragma unroll
            for (int ni = 0; ni < 4; ++ni) {
                bf16x8 kf = *(const bf16x8*)&Ks[(ni * 16 + l16) * 128 +
                                                ((((ks << 2) + quad) ^ (l16 & 7)) << 3)];
                sacc[0][ni] = __builtin_amdgcn_mfma_f32_16x16x32_bf16(qf[0][ks], kf, sacc[0][ni], 0, 0, 0);
                sacc[1][ni] = __builtin_amdgcn_mfma_f32_16x16x32_bf16(qf[1][ks], kf, sacc[1][ni], 0, 0, 0);
            }

        // register online softmax + P write (per-wave LDS, no barrier needed)
        float al[2][4];
#pragma unroll
        for (int mi = 0; mi < 2; ++mi)
#pragma unroll
            for (int reg = 0; reg < 4; ++reg) {
                int rloc = mi * 16 + quad * 4 + reg;
                int qrow = r0 + rloc;
                float sv[4];
                float mx = -1e30f;
#pragma unroll
                for (int ni = 0; ni < 4; ++ni) {
                    float v = sacc[mi][ni][reg] * SCALE;
                    int key = kt * 64 + ni * 16 + l16;
                    if (key > qrow) v = -1e30f;
                    sv[ni] = v;
                    mx = fmaxf(mx, v);
                }
                mx = fmaxf(mx, __shfl_xor(mx, 1));
                mx = fmaxf(mx, __shfl_xor(mx, 2));
                mx = fmaxf(mx, __shfl_xor(mx, 4));
                mx = fmaxf(mx, __shfl_xor(mx, 8));
                float mold = mrow[mi][reg];
                float mnew = fmaxf(mold, mx);
                float a    = __expf(mold - mnew);
                float rs   = 0.f;
#pragma unroll
                for (int ni = 0; ni < 4; ++ni) {
                    float p = __expf(sv[ni] - mnew);
                    rs += p;
                    int blk = (ni * 2 + (l16 >> 3)) ^ (rloc & 7);
                    Ps[wave][rloc * 64 + blk * 8 + (l16 & 7)] = (bf16)p;
                }
                rs += __shfl_xor(rs, 1);
                rs += __shfl_xor(rs, 2);
                rs += __shfl_xor(rs, 4);
                rs += __shfl_xor(rs, 8);
                mrow[mi][reg] = mnew;
                lrow[mi][reg] = lrow[mi][reg] * a + rs;
                al[mi][reg]   = a;
            }

        // rescale O, then O += P @ V
#pragma unroll
        for (int mi = 0; mi < 2; ++mi)
#pragma unroll
            for (int ni = 0; ni < 8; ++ni)
#pragma unroll
                for (int reg = 0; reg < 4; ++reg)
                    o_acc[mi][ni][reg] *= al[mi][reg];
#pragma unroll
        for (int ks2 = 0; ks2 < 2; ++ks2) {
            bf16x8 pa[2];
#pragma unroll
            for (int mi = 0; mi < 2; ++mi) {
                int rloc = mi * 16 + l16;
                pa[mi] = *(const bf16x8*)&Ps[wave][rloc * 64 +
                                                   ((((ks2 << 2) + quad) ^ (rloc & 7)) << 3)];
            }
#pragma unroll
            for (int ni = 0; ni < 8; ++ni) {
                int d = ni * 16 + l16;
                bf16x8 vf = *(const bf16x8*)&Vt[d * 64 + ((((ks2 << 2) + quad) ^ (d & 7)) << 3)];
                o_acc[0][ni] = __builtin_amdgcn_mfma_f32_16x16x32_bf16(pa[0], vf, o_acc[0][ni], 0, 0, 0);
                o_acc[1][ni] = __builtin_amdgcn_mfma_f32_16x16x32_bf16(pa[1], vf, o_acc[1][ni], 0, 0, 0);
            }
        }
        __syncthreads();
    }

    // epilogue
#pragma unroll
    for (int mi = 0; mi < 2; ++mi)
#pragma unroll
        for (int reg = 0; reg < 4; ++reg) {
            float linv = 1.f / fmaxf(lrow[mi][reg], 1e-20f);
            int s = r0 + mi * 16 + quad * 4 + reg;
#pragma unroll
            for (int ni = 0; ni < 8; ++ni)
                obuf[(size_t)s * HID + h * HD + ni * 16 + l16] =
                    (bf16)(o_acc[mi][ni][reg] * linv);
        }
}

// ===========================================================================
// Fallback path (round-3, proven): used only if ws_size is too small.
// ===========================================================================
template <typename TA, typename TO>
__global__ __launch_bounds__(256) void gemm_bt(const TA* __restrict__ A,
                                               const float* __restrict__ W,
                                               const float* __restrict__ bias,
                                               TO* __restrict__ out,
                                               int N, int K) {
    __shared__ __align__(16) bf16 As[128 * 64];
    __shared__ __align__(16) bf16 Bs[128 * 64];
    const int tid = threadIdx.x, wave = tid >> 6, lane = tid & 63;
    const int quad = lane >> 4, l16 = lane & 15, wm = wave >> 1, wn = wave & 1;
    const int row0 = blockIdx.y * 128, col0 = blockIdx.x * 128;
    f32x4 acc[4][4];
#pragma unroll
    for (int mi = 0; mi < 4; ++mi)
#pragma unroll
        for (int ni = 0; ni < 4; ++ni) { f32x4 z = {0.f,0.f,0.f,0.f}; acc[mi][ni] = z; }
    for (int k0 = 0; k0 < K; k0 += 64) {
#pragma unroll
        for (int i = 0; i < 4; ++i) {
            int c = i * 256 + tid, r = c >> 3, col8 = (c & 7) << 3;
            *(bf16x8*)&As[r * 64 + col8] = load8(&A[(size_t)(row0 + r) * K + k0 + col8]);
            *(bf16x8*)&Bs[r * 64 + col8] = load8(&W[(size_t)(col0 + r) * K + k0 + col8]);
        }
        __syncthreads();
#pragma unroll
        for (int ks = 0; ks < 2; ++ks) {
            bf16x8 af[4], bfr[4];
#pragma unroll
            for (int mi = 0; mi < 4; ++mi)
                af[mi] = *(const bf16x8*)&As[(wm * 64 + mi * 16 + l16) * 64 + ks * 32 + quad * 8];
#pragma unroll
            for (int ni = 0; ni < 4; ++ni)
                bfr[ni] = *(const bf16x8*)&Bs[(wn * 64 + ni * 16 + l16) * 64 + ks * 32 + quad * 8];
#pragma unroll
            for (int mi = 0; mi < 4; ++mi)
#pragma unroll
                for (int ni = 0; ni < 4; ++ni)
                    acc[mi][ni] = __builtin_amdgcn_mfma_f32_16x16x32_bf16(af[mi], bfr[ni], acc[mi][ni], 0, 0, 0);
        }
        __syncthreads();
    }
#pragma unroll
    for (int ni = 0; ni < 4; ++ni) {
        int n = col0 + wn * 64 + ni * 16 + l16;
        float bv = bias[n];
#pragma unroll
        for (int mi = 0; mi < 4; ++mi) {
            int m = row0 + wm * 64 + mi * 16 + quad * 4;
#pragma unroll
            for (int reg = 0; reg < 4; ++reg)
                out[(size_t)(m + reg) * N + n] = (TO)(acc[mi][ni][reg] + bv);
        }
    }
}

__global__ __launch_bounds__(256) void attn_old(const bf16* __restrict__ qbuf,
                                                const bf16* __restrict__ kbuf,
                                                const bf16* __restrict__ vbuf,
                                                bf16* __restrict__ obuf) {
    const int qi = blockIdx.x, hh = blockIdx.y, kvh = hh >> 2;
    __shared__ __align__(16) bf16 Qs[64 * 128];
    __shared__ __align__(16) bf16 Ks2[64 * 128];
    __shared__ __align__(16) bf16 Vt2[128 * 80];
    __shared__ __align__(16) float Ss[64 * 64];
    __shared__ __align__(16) bf16 Ps2[64 * 64];
    __shared__ float mS[64], lS[64], aS[64];
    const int tid = threadIdx.x, wave = tid >> 6, lane = tid & 63;
    const int quad = lane >> 4, l16 = lane & 15;
#pragma unroll
    for (int i = 0; i < 4; ++i) {
        int c = i * 256 + tid, r = c >> 4, col8 = (c & 15) << 3;
        *(int4*)&Qs[r * 128 + col8] = *(const int4*)&qbuf[(size_t)(qi * 64 + r) * HID + hh * HD + col8];
    }
    if (tid < 64) { mS[tid] = -1e30f; lS[tid] = 0.f; }
    f32x4 o_acc[8];
#pragma unroll
    for (int i = 0; i < 8; ++i) { f32x4 z = {0.f,0.f,0.f,0.f}; o_acc[i] = z; }
    __syncthreads();
    for (int kt = 0; kt <= qi; ++kt) {
#pragma unroll
        for (int i = 0; i < 4; ++i) {
            int c = i * 256 + tid, r = c >> 4, col8 = (c & 15) << 3;
            const size_t gofs = (size_t)(kt * 64 + r) * (NKV * HD) + kvh * HD + col8;
            *(int4*)&Ks2[r * 128 + col8] = *(const int4*)&kbuf[gofs];
            bf16x8 vv = *(const bf16x8*)&vbuf[gofs];
#pragma unroll
            for (int e = 0; e < 8; ++e) Vt2[(col8 + e) * 80 + r] = vv[e];
        }
        __syncthreads();
        f32x4 sacc[4];
#pragma unroll
        for (int ni = 0; ni < 4; ++ni) { f32x4 z = {0.f,0.f,0.f,0.f}; sacc[ni] = z; }
#pragma unroll
        for (int ks = 0; ks < 4; ++ks) {
            bf16x8 a = *(const bf16x8*)&Qs[(wave * 16 + l16) * 128 + ks * 32 + quad * 8];
#pragma unroll
            for (int ni = 0; ni < 4; ++ni) {
                bf16x8 b = *(const bf16x8*)&Ks2[(ni * 16 + l16) * 128 + ks * 32 + quad * 8];
                sacc[ni] = __builtin_amdgcn_mfma_f32_16x16x32_bf16(a, b, sacc[ni], 0, 0, 0);
            }
        }
#pragma unroll
        for (int ni = 0; ni < 4; ++ni)
#pragma unroll
            for (int reg = 0; reg < 4; ++reg) {
                int r = wave * 16 + quad * 4 + reg, cc = ni * 16 + l16;
                float sv = sacc[ni][reg] * SCALE;
                if (kt * 64 + cc > qi * 64 + r) sv = -1e30f;
                Ss[r * 64 + cc] = sv;
            }
        __syncthreads();
        {
            int r = tid >> 2, j = tid & 3;
            float vals[16], mloc = -1e30f;
#pragma unroll
            for (int c = 0; c < 16; ++c) { vals[c] = Ss[r * 64 + j * 16 + c]; mloc = fmaxf(mloc, vals[c]); }
            mloc = fmaxf(mloc, __shfl_xor(mloc, 1));
            mloc = fmaxf(mloc, __shfl_xor(mloc, 2));
            float mold = mS[r], mnew = fmaxf(mold, mloc), ssum = 0.f;
#pragma unroll
            for (int c = 0; c < 16; ++c) {
                float p = __expf(vals[c] - mnew);
                ssum += p;
                Ps2[r * 64 + j * 16 + c] = (bf16)p;
            }
            ssum += __shfl_xor(ssum, 1);
            ssum += __shfl_xor(ssum, 2);
            if (j == 0) { float alpha = __expf(mold - mnew); mS[r] = mnew; lS[r] = lS[r] * alpha + ssum; aS[r] = alpha; }
        }
        __syncthreads();
        {
            float al2[4];
#pragma unroll
            for (int reg = 0; reg < 4; ++reg) al2[reg] = aS[wave * 16 + quad * 4 + reg];
#pragma unroll
            for (int ni = 0; ni < 8; ++ni)
#pragma unroll
                for (int reg = 0; reg < 4; ++reg) o_acc[ni][reg] *= al2[reg];
#pragma unroll
            for (int ks = 0; ks < 2; ++ks) {
                bf16x8 a = *(const bf16x8*)&Ps2[(wave * 16 + l16) * 64 + ks * 32 + quad * 8];
#pragma unroll
                for (int ni = 0; ni < 8; ++ni) {
                    bf16x8 b = *(const bf16x8*)&Vt2[(ni * 16 + l16) * 80 + ks * 32 + quad * 8];
                    o_acc[ni] = __builtin_amdgcn_mfma_f32_16x16x32_bf16(a, b, o_acc[ni], 0, 0, 0);
                }
            }
        }
        __syncthreads();
    }
    {
        float linv[4];
#pragma unroll
        for (int reg = 0; reg < 4; ++reg) linv[reg] = 1.f / fmaxf(lS[wave * 16 + quad * 4 + reg], 1e-20f);
#pragma unroll
        for (int ni = 0; ni < 8; ++ni)
#pragma unroll
            for (int reg = 0; reg < 4; ++reg) {
                int r = wave * 16 + quad * 4 + reg;
                obuf[(size_t)(qi * 64 + r) * HID + hh * HD + ni * 16 + l16] = (bf16)(o_acc[ni][reg] * linv[reg]);
            }
    }
}

// ---------------------------------------------------------------------------
extern "C" void kernel_launch(void* const* d_in, const int* in_sizes, int n_in,
                              void* d_out, int out_size, void* d_ws, size_t ws_size,
                              hipStream_t stream) {
    const float* x   = (const float*)d_in[0];
    const float* Wq  = (const float*)d_in[1];
    const float* bq  = (const float*)d_in[2];
    const float* Wk  = (const float*)d_in[3];
    const float* bk  = (const float*)d_in[4];
    const float* Wv  = (const float*)d_in[5];
    const float* bv  = (const float*)d_in[6];
    const float* Wo  = (const float*)d_in[7];
    const float* bo  = (const float*)d_in[8];
    const float* qg  = (const float*)d_in[9];
    const float* qbt = (const float*)d_in[10];
    const float* kg  = (const float*)d_in[11];
    const float* kbt = (const float*)d_in[12];
    float* out = (float*)d_out;

    const size_t NEED = 142606336;  // fast-path workspace bytes
    if (ws_size >= NEED) {
        char* p = (char*)d_ws;
        bf16* xb  = (bf16*)p; p += 16777216;
        bf16* Wqb = (bf16*)p; p += 33554432;
        bf16* Wkb = (bf16*)p; p += 8388608;
        bf16* Wvb = (bf16*)p; p += 8388608;
        bf16* Wob = (bf16*)p; p += 33554432;
        bf16* qbuf = (bf16*)p; p += 16777216;
        bf16* kbuf = (bf16*)p; p += 4194304;
        bf16* vbT  = (bf16*)p; p += 4194304;
        bf16* abuf = (bf16*)p;

        // fp32 -> bf16 conversions
        cvt<<<4096, 256, 0, stream>>>(x,  xb,  1048576);
        cvt<<<8192, 256, 0, stream>>>(Wq, Wqb, 2097152);
        cvt<<<2048, 256, 0, stream>>>(Wk, Wkb, 524288);
        cvt<<<2048, 256, 0, stream>>>(Wv, Wvb, 524288);
        cvt<<<8192, 256, 0, stream>>>(Wo, Wob, 2097152);

        // projections (m97-style)
        gemm_lds<false, bf16><<<dim3(32, 16), 256, 0, stream>>>(xb, Wqb, bq, qbuf, 4096, 4096);
        gemm_lds<false, bf16><<<dim3(8, 16), 256, 0, stream>>>(xb, Wkb, bk, kbuf, 1024, 4096);
        // V transposed: vbT[col][s] = Wv[col] . x[s] + bv[col]
        gemm_lds<true, bf16><<<dim3(16, 8), 256, 0, stream>>>(Wvb, xb, bv, vbT, 2048, 4096);

        ln_rope<<<dim3((S_LEN * (NH + NKV)) / 4), 256, 0, stream>>>(qbuf, kbuf, qg, qbt, kg, kbt);

        attn2<<<dim3(64, 8), 256, 0, stream>>>(qbuf, kbuf, vbT, abuf);

        gemm_lds<false, float><<<dim3(32, 16), 256, 0, stream>>>(abuf, Wob, bo, out, 4096, 4096);
    } else {
        // fallback: round-3 pipeline (needs 40 MB)
        char* ws   = (char*)d_ws;
        bf16* qbuf = (bf16*)(ws);
        bf16* kbuf = (bf16*)(ws + (16u << 20));
        bf16* vbuf = (bf16*)(ws + (20u << 20));
        bf16* abuf = (bf16*)(ws + (24u << 20));
        gemm_bt<float, bf16><<<dim3(32, 16), 256, 0, stream>>>(x, Wq, bq, qbuf, 4096, 4096);
        gemm_bt<float, bf16><<<dim3(8, 16), 256, 0, stream>>>(x, Wk, bk, kbuf, 1024, 4096);
        gemm_bt<float, bf16><<<dim3(8, 16), 256, 0, stream>>>(x, Wv, bv, vbuf, 1024, 4096);
        ln_rope<<<dim3((S_LEN * (NH + NKV)) / 4), 256, 0, stream>>>(qbuf, kbuf, qg, qbt, kg, kbt);
        attn_old<<<dim3(32, 32), 256, 0, stream>>>(qbuf, kbuf, vbuf, abuf);
        gemm_bt<bf16, float><<<dim3(32, 16), 256, 0, stream>>>(abuf, Wo, bo, out, 4096, 4096);
    }
}

// Round 5
// 695.646 us; speedup vs baseline: 1.8047x; 1.1707x over previous
//
#include <hip/hip_runtime.h>

typedef __bf16 bf16;
typedef __bf16 bf16x8 __attribute__((ext_vector_type(8)));
typedef __bf16 bf16x4 __attribute__((ext_vector_type(4)));
typedef float f32x4 __attribute__((ext_vector_type(4)));

#define S_LEN 2048
#define HID 4096
#define NH 32
#define NKV 8
#define HD 128
#define QSTR 6144                      // fused qkv row stride
#define SCALE 0.08838834764831845f
#define QSCL 0.1275164918918885f       // SCALE * log2(e)
#define M2C 16.33f                     // >= 128*QSCL = 16.3221 (Cauchy-Schwarz hard bound)

__device__ __forceinline__ bf16x8 load8(const bf16* p) { return *(const bf16x8*)p; }
__device__ __forceinline__ bf16x8 load8(const float* p) {
    float4 a = *(const float4*)p;
    float4 b = *(const float4*)(p + 4);
    bf16x8 r;
    r[0] = (bf16)a.x; r[1] = (bf16)a.y; r[2] = (bf16)a.z; r[3] = (bf16)a.w;
    r[4] = (bf16)b.x; r[5] = (bf16)b.y; r[6] = (bf16)b.z; r[7] = (bf16)b.w;
    return r;
}

__device__ __forceinline__ void load_lds16(const bf16* g, bf16* l) {
    __builtin_amdgcn_global_load_lds(
        (const __attribute__((address_space(1))) void*)g,
        (__attribute__((address_space(3))) void*)l, 16, 0, 0);
}

// ---------------------------------------------------------------------------
// fp32 -> bf16 bulk convert
// ---------------------------------------------------------------------------
__global__ __launch_bounds__(256) void cvt(const float* __restrict__ in,
                                           bf16* __restrict__ out, int n8) {
    int i = blockIdx.x * 256 + threadIdx.x;
    if (i < n8) *(bf16x8*)&out[i * 8] = load8(&in[(size_t)i * 8]);
}

// ---------------------------------------------------------------------------
// m97-style GEMM: out[M,N] = A[M,K] @ B[N,K]^T + bias  (bf16 in, fp32 accum)
// BM=0: bias=b0[n].  BM=1: packed-QKV bias (b0 cols<4096, b1 <5120, b2 else).
// ---------------------------------------------------------------------------
template <int BM, typename TO>
__global__ __launch_bounds__(256) void gemm_lds(const bf16* __restrict__ A,
                                                const bf16* __restrict__ Bw,
                                                const float* __restrict__ b0,
                                                const float* __restrict__ b1,
                                                const float* __restrict__ b2,
                                                TO* __restrict__ out,
                                                int N, int K) {
    __shared__ __align__(16) bf16 As[128 * 64];
    __shared__ __align__(16) bf16 Bs[128 * 64];

    const int tid  = threadIdx.x;
    const int wave = tid >> 6;
    const int lane = tid & 63;
    const int quad = lane >> 4;
    const int l16  = lane & 15;
    const int wm   = wave >> 1;
    const int wn   = wave & 1;
    const int row0 = blockIdx.y * 128;
    const int col0 = blockIdx.x * 128;

    f32x4 acc[4][4];
#pragma unroll
    for (int mi = 0; mi < 4; ++mi)
#pragma unroll
        for (int ni = 0; ni < 4; ++ni) {
            f32x4 z = {0.f, 0.f, 0.f, 0.f};
            acc[mi][ni] = z;
        }

    for (int k0 = 0; k0 < K; k0 += 64) {
#pragma unroll
        for (int i = 0; i < 4; ++i) {
            int c    = i * 256 + tid;
            int r    = c >> 3;
            int col8 = (c & 7) << 3;
            load_lds16(&A[(size_t)(row0 + r) * K + k0 + col8], &As[c * 8]);
            load_lds16(&Bw[(size_t)(col0 + r) * K + k0 + col8], &Bs[c * 8]);
        }
        __syncthreads();

#pragma unroll
        for (int ks = 0; ks < 2; ++ks) {
            bf16x8 af[4], bfr[4];
#pragma unroll
            for (int mi = 0; mi < 4; ++mi)
                af[mi] = *(const bf16x8*)&As[(wm * 64 + mi * 16 + l16) * 64 + ks * 32 + quad * 8];
#pragma unroll
            for (int ni = 0; ni < 4; ++ni)
                bfr[ni] = *(const bf16x8*)&Bs[(wn * 64 + ni * 16 + l16) * 64 + ks * 32 + quad * 8];
#pragma unroll
            for (int mi = 0; mi < 4; ++mi)
#pragma unroll
                for (int ni = 0; ni < 4; ++ni)
                    acc[mi][ni] = __builtin_amdgcn_mfma_f32_16x16x32_bf16(
                        af[mi], bfr[ni], acc[mi][ni], 0, 0, 0);
        }
        __syncthreads();
    }

#pragma unroll
    for (int ni = 0; ni < 4; ++ni) {
        int n = col0 + wn * 64 + ni * 16 + l16;
        float bv;
        if (BM == 0) bv = b0[n];
        else bv = (n < 4096) ? b0[n] : ((n < 5120) ? b1[n - 4096] : b2[n - 5120]);
#pragma unroll
        for (int mi = 0; mi < 4; ++mi) {
            int m = row0 + wm * 64 + mi * 16 + quad * 4;
#pragma unroll
            for (int reg = 0; reg < 4; ++reg)
                out[(size_t)(m + reg) * N + n] = (TO)(acc[mi][ni][reg] + bv);
        }
    }
}

// ---------------------------------------------------------------------------
// LayerNorm(HD=128) + RoPE in place on fused qkv buffer (stride QSTR).
// q rows additionally pre-scaled by QSCL (softmax works in log2 domain).
// ---------------------------------------------------------------------------
__global__ __launch_bounds__(256) void ln_rope(bf16* __restrict__ qkv,
                                               const float* __restrict__ qg, const float* __restrict__ qbt,
                                               const float* __restrict__ kg, const float* __restrict__ kbt) {
    int row  = blockIdx.x * 4 + (threadIdx.x >> 6);
    int lane = threadIdx.x & 63;

    bf16* ptr;
    const float *g, *bb;
    int s;
    float osc;
    if (row < S_LEN * NH) {
        s   = row >> 5;
        ptr = qkv + (size_t)s * QSTR + (row & 31) * HD;
        g   = qg; bb = qbt; osc = QSCL;
    } else {
        int r2 = row - S_LEN * NH;
        s   = r2 >> 3;
        ptr = qkv + (size_t)s * QSTR + 4096 + (r2 & 7) * HD;
        g   = kg; bb = kbt; osc = 1.f;
    }

    float x1 = (float)ptr[lane];
    float x2 = (float)ptr[lane + 64];
    float sum = x1 + x2;
    float sq  = x1 * x1 + x2 * x2;
#pragma unroll
    for (int m = 1; m < 64; m <<= 1) {
        sum += __shfl_xor(sum, m);
        sq  += __shfl_xor(sq, m);
    }
    float mu  = sum * (1.f / 128.f);
    float var = sq * (1.f / 128.f) - mu * mu;
    float rs  = rsqrtf(var + 1e-5f);
    float n1  = (x1 - mu) * rs * g[lane] + bb[lane];
    float n2  = (x2 - mu) * rs * g[lane + 64] + bb[lane + 64];

    float inv = powf(500000.f, -(float)lane * (1.f / 64.f));
    float ang = (float)s * inv;
    float sn, cs;
    sincosf(ang, &sn, &cs);

    ptr[lane]      = (bf16)((n1 * cs - n2 * sn) * osc);
    ptr[lane + 64] = (bf16)((n2 * cs + n1 * sn) * osc);
}

// ---------------------------------------------------------------------------
// Transpose v (cols 5120..6143 of qkv, [s][c]) -> vT [c][s]. 64x64 LDS tiles,
// XOR-swizzled (write b128 free; read 8xb16 2-way = free).
// ---------------------------------------------------------------------------
__global__ __launch_bounds__(256) void transpose_v(const bf16* __restrict__ qkv,
                                                   bf16* __restrict__ vT) {
    __shared__ bf16 Ts[64 * 64];
    const int c0 = blockIdx.x * 64;
    const int s0 = blockIdx.y * 64;
    const int tid = threadIdx.x;

#pragma unroll
    for (int i = 0; i < 2; ++i) {
        int cc = i * 256 + tid;
        int r = cc >> 3, col8 = cc & 7;
        *(bf16x8*)&Ts[r * 64 + ((col8 ^ (r & 7)) << 3)] =
            *(const bf16x8*)&qkv[(size_t)(s0 + r) * QSTR + 5120 + c0 + (col8 << 3)];
    }
    __syncthreads();
#pragma unroll
    for (int i = 0; i < 2; ++i) {
        int oc = i * 256 + tid;
        int c = oc & 63, sb = oc >> 6;
        bf16x8 r8;
#pragma unroll
        for (int j = 0; j < 8; ++j) {
            int sg = sb * 8 + j;
            r8[j] = Ts[sg * 64 + ((((c >> 3) ^ (sg & 7)) << 3) + (c & 7))];
        }
        *(bf16x8*)&vT[(size_t)(c0 + c) * S_LEN + s0 + sb * 8] = r8;
    }
}

// ---------------------------------------------------------------------------
// Flash attention v3: fixed-max softmax (log2 domain), balanced split-K.
// Block = (pair p, split sp, kvh). Processes Q-tiles p and 63-p (32 rows),
// K-tiles kt == sp (mod 2). Wave w owns head kvh*4+w. Register-prefetched
// staging. Row sums via MFMA ones-trick. Writes fp32 partials OP[sp] + l.
// ---------------------------------------------------------------------------
__global__ __launch_bounds__(256, 2) void attn3(const bf16* __restrict__ qkv,
                                                const bf16* __restrict__ vT,
                                                float* __restrict__ OP,
                                                float* __restrict__ lbuf) {
    const int pairp = blockIdx.x >> 1;
    const int sp    = blockIdx.x & 1;
    const int kvh   = blockIdx.y;
    const int tid   = threadIdx.x;
    const int wave  = tid >> 6;
    const int lane  = tid & 63;
    const int quad  = lane >> 4;
    const int l16   = lane & 15;
    const int h     = kvh * 4 + wave;

    __shared__ __align__(16) bf16 Ks[64 * 128];
    __shared__ __align__(16) bf16 Vt[128 * 64];
    __shared__ __align__(16) bf16 Ps[4][32 * 64];

    float* OPs = OP + (size_t)sp * (S_LEN * HID);
    float* lbs = lbuf + sp * (S_LEN * NH);

    bf16x8 onesf;
#pragma unroll
    for (int j = 0; j < 8; ++j) onesf[j] = (bf16)1.f;

    int4 pk[4], pv[4];

    for (int ph = 0; ph < 2; ++ph) {
        const int qt  = ph ? (63 - pairp) : pairp;
        const int r0  = qt * 32;
        const int nkt = qt / 2 + 1;
        const int nit = (nkt + 1 - sp) / 2;   // kt = sp + 2*it < nkt

        // Q fragments (already scaled by QSCL in ln_rope)
        bf16x8 qf[2][4];
#pragma unroll
        for (int mi = 0; mi < 2; ++mi)
#pragma unroll
            for (int ks = 0; ks < 4; ++ks)
                qf[mi][ks] = *(const bf16x8*)&qkv[(size_t)(r0 + mi * 16 + l16) * QSTR +
                                                  h * HD + ks * 32 + quad * 8];

        f32x4 o_acc[2][8];
#pragma unroll
        for (int mi = 0; mi < 2; ++mi)
#pragma unroll
            for (int ni = 0; ni < 8; ++ni) {
                f32x4 z = {0.f, 0.f, 0.f, 0.f};
                o_acc[mi][ni] = z;
            }
        f32x4 lacc[2];
#pragma unroll
        for (int mi = 0; mi < 2; ++mi) { f32x4 z = {0.f, 0.f, 0.f, 0.f}; lacc[mi] = z; }

        auto load_regs = [&](int kt) {
#pragma unroll
            for (int i = 0; i < 4; ++i) {
                int cc = i * 256 + tid;
                int key = cc >> 4, d8 = cc & 15;
                pk[i] = *(const int4*)&qkv[(size_t)(kt * 64 + key) * QSTR + 4096 +
                                           kvh * HD + (d8 << 3)];
            }
#pragma unroll
            for (int i = 0; i < 4; ++i) {
                int cc = i * 256 + tid;
                int d = cc >> 3, k8 = cc & 7;
                pv[i] = *(const int4*)&vT[(size_t)(kvh * HD + d) * S_LEN + kt * 64 + (k8 << 3)];
            }
        };

        if (nit > 0) load_regs(sp);

        for (int it = 0; it < nit; ++it) {
            const int kt = sp + 2 * it;
            // drain prefetch regs into swizzled LDS
#pragma unroll
            for (int i = 0; i < 4; ++i) {
                int cc = i * 256 + tid;
                int key = cc >> 4, d8 = cc & 15;
                *(int4*)&Ks[key * 128 + ((d8 ^ (key & 7)) << 3)] = pk[i];
            }
#pragma unroll
            for (int i = 0; i < 4; ++i) {
                int cc = i * 256 + tid;
                int d = cc >> 3, k8 = cc & 7;
                *(int4*)&Vt[d * 64 + ((k8 ^ (d & 7)) << 3)] = pv[i];
            }
            __syncthreads();

            if (it + 1 < nit) load_regs(kt + 2);   // prefetch next tile

            // S = Q K^T (log2-scaled)
            f32x4 sacc[2][4];
#pragma unroll
            for (int mi = 0; mi < 2; ++mi)
#pragma unroll
                for (int ni = 0; ni < 4; ++ni) {
                    f32x4 z = {0.f, 0.f, 0.f, 0.f};
                    sacc[mi][ni] = z;
                }
#pragma unroll
            for (int ks = 0; ks < 4; ++ks)
#pragma unroll
                for (int ni = 0; ni < 4; ++ni) {
                    bf16x8 kf = *(const bf16x8*)&Ks[(ni * 16 + l16) * 128 +
                                                    ((((ks << 2) + quad) ^ (l16 & 7)) << 3)];
                    sacc[0][ni] = __builtin_amdgcn_mfma_f32_16x16x32_bf16(qf[0][ks], kf, sacc[0][ni], 0, 0, 0);
                    sacc[1][ni] = __builtin_amdgcn_mfma_f32_16x16x32_bf16(qf[1][ks], kf, sacc[1][ni], 0, 0, 0);
                }

            // fixed-max softmax: p = exp2(s2 - M2C); masked -> 0
#pragma unroll
            for (int mi = 0; mi < 2; ++mi)
#pragma unroll
                for (int reg = 0; reg < 4; ++reg) {
                    int rloc = mi * 16 + quad * 4 + reg;
                    int qrow = r0 + rloc;
#pragma unroll
                    for (int ni = 0; ni < 4; ++ni) {
                        int key = kt * 64 + ni * 16 + l16;
                        float t = (key > qrow) ? -1e30f : (sacc[mi][ni][reg] - M2C);
                        float p = exp2f(t);
                        int blk = (ni * 2 + (l16 >> 3)) ^ (rloc & 7);
                        Ps[wave][rloc * 64 + blk * 8 + (l16 & 7)] = (bf16)p;
                    }
                }

            // O += P @ V ; l += P @ ones  (per-wave Ps: no barrier needed)
#pragma unroll
            for (int ks2 = 0; ks2 < 2; ++ks2) {
                bf16x8 pa[2];
#pragma unroll
                for (int mi = 0; mi < 2; ++mi) {
                    int rloc = mi * 16 + l16;
                    pa[mi] = *(const bf16x8*)&Ps[wave][rloc * 64 +
                                                       ((((ks2 << 2) + quad) ^ (rloc & 7)) << 3)];
                }
#pragma unroll
                for (int ni = 0; ni < 8; ++ni) {
                    int d = ni * 16 + l16;
                    bf16x8 vf = *(const bf16x8*)&Vt[d * 64 + ((((ks2 << 2) + quad) ^ (d & 7)) << 3)];
                    o_acc[0][ni] = __builtin_amdgcn_mfma_f32_16x16x32_bf16(pa[0], vf, o_acc[0][ni], 0, 0, 0);
                    o_acc[1][ni] = __builtin_amdgcn_mfma_f32_16x16x32_bf16(pa[1], vf, o_acc[1][ni], 0, 0, 0);
                }
                lacc[0] = __builtin_amdgcn_mfma_f32_16x16x32_bf16(pa[0], onesf, lacc[0], 0, 0, 0);
                lacc[1] = __builtin_amdgcn_mfma_f32_16x16x32_bf16(pa[1], onesf, lacc[1], 0, 0, 0);
            }
            __syncthreads();
        }

        // partial epilogue (always runs; zeros if nit==0)
#pragma unroll
        for (int mi = 0; mi < 2; ++mi)
#pragma unroll
            for (int reg = 0; reg < 4; ++reg) {
                int s = r0 + mi * 16 + quad * 4 + reg;
#pragma unroll
                for (int ni = 0; ni < 8; ++ni)
                    OPs[(size_t)s * HID + h * HD + ni * 16 + l16] = o_acc[mi][ni][reg];
                if (l16 == 0) lbs[s * NH + h] = lacc[mi][reg];
            }
    }
}

// ---------------------------------------------------------------------------
// merge: abuf[s][h*128+d] = (OP0 + OP1) / (l0 + l1)
// ---------------------------------------------------------------------------
__global__ __launch_bounds__(256) void merge(const float* __restrict__ OP,
                                             const float* __restrict__ lb,
                                             bf16* __restrict__ abuf) {
    int g = blockIdx.x * 256 + threadIdx.x;      // 0 .. 2048*1024-1
    int s = g >> 10;
    int col = (g & 1023) << 2;
    int h = col >> 7;
    float l = lb[s * NH + h] + lb[S_LEN * NH + s * NH + h];
    float inv = 1.f / fmaxf(l, 1e-30f);
    f32x4 o0 = *(const f32x4*)&OP[(size_t)g << 2];
    f32x4 o1 = *(const f32x4*)&OP[((size_t)g << 2) + (size_t)S_LEN * HID];
    bf16x4 r;
#pragma unroll
    for (int j = 0; j < 4; ++j) r[j] = (bf16)((o0[j] + o1[j]) * inv);
    *(bf16x4*)&abuf[(size_t)s * HID + col] = r;
}

// ===========================================================================
// Fallback path (round-3, proven) — only if workspace is unexpectedly small.
// ===========================================================================
template <typename TA, typename TO>
__global__ __launch_bounds__(256) void gemm_bt(const TA* __restrict__ A,
                                               const float* __restrict__ W,
                                               const float* __restrict__ bias,
                                               TO* __restrict__ out,
                                               int N, int K) {
    __shared__ __align__(16) bf16 As[128 * 64];
    __shared__ __align__(16) bf16 Bs[128 * 64];
    const int tid = threadIdx.x, wave = tid >> 6, lane = tid & 63;
    const int quad = lane >> 4, l16 = lane & 15, wm = wave >> 1, wn = wave & 1;
    const int row0 = blockIdx.y * 128, col0 = blockIdx.x * 128;
    f32x4 acc[4][4];
#pragma unroll
    for (int mi = 0; mi < 4; ++mi)
#pragma unroll
        for (int ni = 0; ni < 4; ++ni) { f32x4 z = {0.f,0.f,0.f,0.f}; acc[mi][ni] = z; }
    for (int k0 = 0; k0 < K; k0 += 64) {
#pragma unroll
        for (int i = 0; i < 4; ++i) {
            int c = i * 256 + tid, r = c >> 3, col8 = (c & 7) << 3;
            *(bf16x8*)&As[r * 64 + col8] = load8(&A[(size_t)(row0 + r) * K + k0 + col8]);
            *(bf16x8*)&Bs[r * 64 + col8] = load8(&W[(size_t)(col0 + r) * K + k0 + col8]);
        }
        __syncthreads();
#pragma unroll
        for (int ks = 0; ks < 2; ++ks) {
            bf16x8 af[4], bfr[4];
#pragma unroll
            for (int mi = 0; mi < 4; ++mi)
                af[mi] = *(const bf16x8*)&As[(wm * 64 + mi * 16 + l16) * 64 + ks * 32 + quad * 8];
#pragma unroll
            for (int ni = 0; ni < 4; ++ni)
                bfr[ni] = *(const bf16x8*)&Bs[(wn * 64 + ni * 16 + l16) * 64 + ks * 32 + quad * 8];
#pragma unroll
            for (int mi = 0; mi < 4; ++mi)
#pragma unroll
                for (int ni = 0; ni < 4; ++ni)
                    acc[mi][ni] = __builtin_amdgcn_mfma_f32_16x16x32_bf16(af[mi], bfr[ni], acc[mi][ni], 0, 0, 0);
        }
        __syncthreads();
    }
#pragma unroll
    for (int ni = 0; ni < 4; ++ni) {
        int n = col0 + wn * 64 + ni * 16 + l16;
        float bv = bias[n];
#pragma unroll
        for (int mi = 0; mi < 4; ++mi) {
            int m = row0 + wm * 64 + mi * 16 + quad * 4;
#pragma unroll
            for (int reg = 0; reg < 4; ++reg)
                out[(size_t)(m + reg) * N + n] = (TO)(acc[mi][ni][reg] + bv);
        }
    }
}

__global__ __launch_bounds__(256) void ln_rope_f(bf16* __restrict__ qb, bf16* __restrict__ kb,
                                                 const float* __restrict__ qg, const float* __restrict__ qbt,
                                                 const float* __restrict__ kg, const float* __restrict__ kbt) {
    int row = blockIdx.x * 4 + (threadIdx.x >> 6);
    int lane = threadIdx.x & 63;
    bf16* ptr; const float *g, *bb; int s;
    if (row < S_LEN * NH) { s = row >> 5; ptr = qb + (size_t)s * (NH * HD) + (row & 31) * HD; g = qg; bb = qbt; }
    else { int r2 = row - S_LEN * NH; s = r2 >> 3; ptr = kb + (size_t)s * (NKV * HD) + (r2 & 7) * HD; g = kg; bb = kbt; }
    float x1 = (float)ptr[lane], x2 = (float)ptr[lane + 64];
    float sum = x1 + x2, sq = x1 * x1 + x2 * x2;
#pragma unroll
    for (int m = 1; m < 64; m <<= 1) { sum += __shfl_xor(sum, m); sq += __shfl_xor(sq, m); }
    float mu = sum * (1.f / 128.f), var = sq * (1.f / 128.f) - mu * mu;
    float rs = rsqrtf(var + 1e-5f);
    float n1 = (x1 - mu) * rs * g[lane] + bb[lane];
    float n2 = (x2 - mu) * rs * g[lane + 64] + bb[lane + 64];
    float inv = powf(500000.f, -(float)lane * (1.f / 64.f));
    float ang = (float)s * inv, sn, cs;
    sincosf(ang, &sn, &cs);
    ptr[lane] = (bf16)(n1 * cs - n2 * sn);
    ptr[lane + 64] = (bf16)(n2 * cs + n1 * sn);
}

__global__ __launch_bounds__(256) void attn_old(const bf16* __restrict__ qbuf,
                                                const bf16* __restrict__ kbuf,
                                                const bf16* __restrict__ vbuf,
                                                bf16* __restrict__ obuf) {
    const int qi = blockIdx.x, hh = blockIdx.y, kvh = hh >> 2;
    __shared__ __align__(16) bf16 Qs[64 * 128];
    __shared__ __align__(16) bf16 Ks2[64 * 128];
    __shared__ __align__(16) bf16 Vt2[128 * 80];
    __shared__ __align__(16) float Ss[64 * 64];
    __shared__ __align__(16) bf16 Ps2[64 * 64];
    __shared__ float mS[64], lS[64], aS[64];
    const int tid = threadIdx.x, wave = tid >> 6, lane = tid & 63;
    const int quad = lane >> 4, l16 = lane & 15;
#pragma unroll
    for (int i = 0; i < 4; ++i) {
        int c = i * 256 + tid, r = c >> 4, col8 = (c & 15) << 3;
        *(int4*)&Qs[r * 128 + col8] = *(const int4*)&qbuf[(size_t)(qi * 64 + r) * HID + hh * HD + col8];
    }
    if (tid < 64) { mS[tid] = -1e30f; lS[tid] = 0.f; }
    f32x4 o_acc[8];
#pragma unroll
    for (int i = 0; i < 8; ++i) { f32x4 z = {0.f,0.f,0.f,0.f}; o_acc[i] = z; }
    __syncthreads();
    for (int kt = 0; kt <= qi; ++kt) {
#pragma unroll
        for (int i = 0; i < 4; ++i) {
            int c = i * 256 + tid, r = c >> 4, col8 = (c & 15) << 3;
            const size_t gofs = (size_t)(kt * 64 + r) * (NKV * HD) + kvh * HD + col8;
            *(int4*)&Ks2[r * 128 + col8] = *(const int4*)&kbuf[gofs];
            bf16x8 vv = *(const bf16x8*)&vbuf[gofs];
#pragma unroll
            for (int e = 0; e < 8; ++e) Vt2[(col8 + e) * 80 + r] = vv[e];
        }
        __syncthreads();
        f32x4 sacc[4];
#pragma unroll
        for (int ni = 0; ni < 4; ++ni) { f32x4 z = {0.f,0.f,0.f,0.f}; sacc[ni] = z; }
#pragma unroll
        for (int ks = 0; ks < 4; ++ks) {
            bf16x8 a = *(const bf16x8*)&Qs[(wave * 16 + l16) * 128 + ks * 32 + quad * 8];
#pragma unroll
            for (int ni = 0; ni < 4; ++ni) {
                bf16x8 b = *(const bf16x8*)&Ks2[(ni * 16 + l16) * 128 + ks * 32 + quad * 8];
                sacc[ni] = __builtin_amdgcn_mfma_f32_16x16x32_bf16(a, b, sacc[ni], 0, 0, 0);
            }
        }
#pragma unroll
        for (int ni = 0; ni < 4; ++ni)
#pragma unroll
            for (int reg = 0; reg < 4; ++reg) {
                int r = wave * 16 + quad * 4 + reg, cc = ni * 16 + l16;
                float sv = sacc[ni][reg] * SCALE;
                if (kt * 64 + cc > qi * 64 + r) sv = -1e30f;
                Ss[r * 64 + cc] = sv;
            }
        __syncthreads();
        {
            int r = tid >> 2, j = tid & 3;
            float vals[16], mloc = -1e30f;
#pragma unroll
            for (int c = 0; c < 16; ++c) { vals[c] = Ss[r * 64 + j * 16 + c]; mloc = fmaxf(mloc, vals[c]); }
            mloc = fmaxf(mloc, __shfl_xor(mloc, 1));
            mloc = fmaxf(mloc, __shfl_xor(mloc, 2));
            float mold = mS[r], mnew = fmaxf(mold, mloc), ssum = 0.f;
#pragma unroll
            for (int c = 0; c < 16; ++c) {
                float p = __expf(vals[c] - mnew);
                ssum += p;
                Ps2[r * 64 + j * 16 + c] = (bf16)p;
            }
            ssum += __shfl_xor(ssum, 1);
            ssum += __shfl_xor(ssum, 2);
            if (j == 0) { float alpha = __expf(mold - mnew); mS[r] = mnew; lS[r] = lS[r] * alpha + ssum; aS[r] = alpha; }
        }
        __syncthreads();
        {
            float al2[4];
#pragma unroll
            for (int reg = 0; reg < 4; ++reg) al2[reg] = aS[wave * 16 + quad * 4 + reg];
#pragma unroll
            for (int ni = 0; ni < 8; ++ni)
#pragma unroll
                for (int reg = 0; reg < 4; ++reg) o_acc[ni][reg] *= al2[reg];
#pragma unroll
            for (int ks = 0; ks < 2; ++ks) {
                bf16x8 a = *(const bf16x8*)&Ps2[(wave * 16 + l16) * 64 + ks * 32 + quad * 8];
#pragma unroll
                for (int ni = 0; ni < 8; ++ni) {
                    bf16x8 b = *(const bf16x8*)&Vt2[(ni * 16 + l16) * 80 + ks * 32 + quad * 8];
                    o_acc[ni] = __builtin_amdgcn_mfma_f32_16x16x32_bf16(a, b, o_acc[ni], 0, 0, 0);
                }
            }
        }
        __syncthreads();
    }
    {
        float linv[4];
#pragma unroll
        for (int reg = 0; reg < 4; ++reg) linv[reg] = 1.f / fmaxf(lS[wave * 16 + quad * 4 + reg], 1e-20f);
#pragma unroll
        for (int ni = 0; ni < 8; ++ni)
#pragma unroll
            for (int reg = 0; reg < 4; ++reg) {
                int r = wave * 16 + quad * 4 + reg;
                obuf[(size_t)(qi * 64 + r) * HID + hh * HD + ni * 16 + l16] = (bf16)(o_acc[ni][reg] * linv[reg]);
            }
    }
}

// ---------------------------------------------------------------------------
extern "C" void kernel_launch(void* const* d_in, const int* in_sizes, int n_in,
                              void* d_out, int out_size, void* d_ws, size_t ws_size,
                              hipStream_t stream) {
    const float* x   = (const float*)d_in[0];
    const float* Wq  = (const float*)d_in[1];
    const float* bq  = (const float*)d_in[2];
    const float* Wk  = (const float*)d_in[3];
    const float* bk  = (const float*)d_in[4];
    const float* Wv  = (const float*)d_in[5];
    const float* bv  = (const float*)d_in[6];
    const float* Wo  = (const float*)d_in[7];
    const float* bo  = (const float*)d_in[8];
    const float* qg  = (const float*)d_in[9];
    const float* qbt = (const float*)d_in[10];
    const float* kg  = (const float*)d_in[11];
    const float* kbt = (const float*)d_in[12];
    float* out = (float*)d_out;

    // fast-path workspace layout (130,547,712 B):
    //   [0, 64MiB)           : xb (16MiB) | Wqkv (48MiB)   -- later aliased by OP (fp32 x2)
    //   [64MiB, 96MiB)       : Wob
    //   [96MiB, 120MiB)      : qkv (24MiB)                 -- later aliased by abuf (16MiB)
    //   [120MiB, 124MiB)     : vT
    //   [124MiB, +512KiB)    : lbuf
    const size_t NEED = 130547712;
    if (ws_size >= NEED) {
        char* p = (char*)d_ws;
        bf16*  xb   = (bf16*)p;
        bf16*  Wqkv = (bf16*)(p + 16777216);
        float* OP   = (float*)p;                       // aliases xb+Wqkv (both dead by attn)
        bf16*  Wob  = (bf16*)(p + 67108864);
        bf16*  qkv  = (bf16*)(p + 100663296);
        bf16*  abuf = (bf16*)(p + 100663296);          // aliases qkv (dead after attn)
        bf16*  vT   = (bf16*)(p + 125829120);
        float* lbuf = (float*)(p + 130023424);

        // fp32 -> bf16: x and packed W_qkv rows [Wq | Wk | Wv], plus Wo
        cvt<<<4096, 256, 0, stream>>>(x,  xb, 1048576);
        cvt<<<8192, 256, 0, stream>>>(Wq, Wqkv, 2097152);
        cvt<<<2048, 256, 0, stream>>>(Wk, Wqkv + (size_t)4096 * 4096, 524288);
        cvt<<<2048, 256, 0, stream>>>(Wv, Wqkv + (size_t)5120 * 4096, 524288);
        cvt<<<8192, 256, 0, stream>>>(Wo, Wob, 2097152);

        // fused QKV projection: [2048 x 6144]
        gemm_lds<1, bf16><<<dim3(48, 16), 256, 0, stream>>>(xb, Wqkv, bq, bk, bv, qkv, QSTR, 4096);

        // LN + RoPE in place (q pre-scaled by QSCL)
        ln_rope<<<dim3((S_LEN * (NH + NKV)) / 4), 256, 0, stream>>>(qkv, qg, qbt, kg, kbt);

        // v -> vT
        transpose_v<<<dim3(16, 32), 256, 0, stream>>>(qkv, vT);

        // balanced split-K attention -> fp32 partials, then merge
        attn3<<<dim3(64, 8), 256, 0, stream>>>(qkv, vT, OP, lbuf);
        merge<<<8192, 256, 0, stream>>>(OP, lbuf, abuf);

        // output projection
        gemm_lds<0, float><<<dim3(32, 16), 256, 0, stream>>>(abuf, Wob, bo, bo, bo, out, 4096, 4096);
    } else {
        char* ws = (char*)d_ws;
        bf16* qbuf = (bf16*)(ws);
        bf16* kbuf = (bf16*)(ws + (16u << 20));
        bf16* vbuf = (bf16*)(ws + (20u << 20));
        bf16* abuf = (bf16*)(ws + (24u << 20));
        gemm_bt<float, bf16><<<dim3(32, 16), 256, 0, stream>>>(x, Wq, bq, qbuf, 4096, 4096);
        gemm_bt<float, bf16><<<dim3(8, 16), 256, 0, stream>>>(x, Wk, bk, kbuf, 1024, 4096);
        gemm_bt<float, bf16><<<dim3(8, 16), 256, 0, stream>>>(x, Wv, bv, vbuf, 1024, 4096);
        ln_rope_f<<<dim3((S_LEN * (NH + NKV)) / 4), 256, 0, stream>>>(qbuf, kbuf, qg, qbt, kg, kbt);
        attn_old<<<dim3(32, 32), 256, 0, stream>>>(qbuf, kbuf, vbuf, abuf);
        gemm_bt<bf16, float><<<dim3(32, 16), 256, 0, stream>>>(abuf, Wo, bo, out, 4096, 4096);
    }
}